// Round 12
// baseline (359.399 us; speedup 1.0000x reference)
//
#include <hip/hip_runtime.h>
#include <hip/hip_fp16.h>
#include <math.h>

#define NE 16
#define HD 1024
#define FD 2048

typedef _Float16 half2v __attribute__((ext_vector_type(2)));

// ws layout (4-byte units)
#define TOPI_OFF 0          // 256 int
#define TOPW_OFF 256        // 256 float
#define CNT_OFF  512        // 16 int
#define PREF_OFF 528        // 16 int
#define SLOT_OFF 544        // 256 int (pair -> slot)
#define INVT_OFF 800        // 256 int (slot -> token)
#define META_OFF 1056       // 2 int: M1, M2
#define TL1_OFF  1060       // 48 int  (e<<8|mt) 16-token tiles
#define TL2_OFF  1120       // 80 int  (e<<8|mt) 8-token tiles
#define XH_OFF   4096                   // xh fp16 [256][1024] = 131072 ints
#define HBUF_OFF (XH_OFF + 131072)      // h  fp16 [256][2048] = 262144 ints
#define Y_OFF    (HBUF_OFF + 262144)    // y  f32  [256][1024]

#if __has_builtin(__builtin_amdgcn_fdot2)
#define FDOT2(a, b, c) __builtin_amdgcn_fdot2(a, b, c, false)
#else
__device__ __forceinline__ float FDOT2(half2v a, half2v b, float c) {
    return fmaf((float)a.x, (float)b.x, fmaf((float)a.y, (float)b.y, c));
}
#endif

// fp4 e2m1 nibble -> fp16 bits (unscaled)
__device__ __forceinline__ int fp4h(int nib) {
    int c = nib & 7;
    int v;
    if (c == 0) v = 0;
    else if (c == 1) v = 14 << 10;                        // 0.5
    else v = (((c >> 1) + 14) << 10) | ((c & 1) << 9);
    v |= (nib & 8) << 12;
    return v;
}

// LUT byte -> 2 packed fp16 times packed pow2 scale (exact)
__device__ __forceinline__ half2v dec2(const int* lut, int byte, int sv) {
    int l = lut[byte & 255];
    __half2 p = *reinterpret_cast<const __half2*>(&l);
    __half2 sc = *reinterpret_cast<const __half2*>(&sv);
    __half2 r = __hmul2(p, sc);
    return *reinterpret_cast<half2v*>(&r);
}

union XF { int4 v; half2v h[4]; };

// paired-merge butterfly: 16 per-lane partials -> per-token totals; lane L gets token (L>>2)
__device__ __forceinline__ float reduce16(const float* v, int lane) {
    float r8[8];
    #pragma unroll
    for (int i = 0; i < 8; ++i) {
        bool hi = lane & 32;
        float keep = hi ? v[i + 8] : v[i];
        float send = hi ? v[i] : v[i + 8];
        r8[i] = keep + __shfl_xor(send, 32);
    }
    float r4[4];
    #pragma unroll
    for (int i = 0; i < 4; ++i) {
        bool hi = lane & 16;
        float keep = hi ? r8[i + 4] : r8[i];
        float send = hi ? r8[i] : r8[i + 4];
        r4[i] = keep + __shfl_xor(send, 16);
    }
    float r2[2];
    #pragma unroll
    for (int i = 0; i < 2; ++i) {
        bool hi = lane & 8;
        float keep = hi ? r4[i + 2] : r4[i];
        float send = hi ? r4[i] : r4[i + 2];
        r2[i] = keep + __shfl_xor(send, 8);
    }
    bool hi = lane & 4;
    float keep = hi ? r2[1] : r2[0];
    float send = hi ? r2[0] : r2[1];
    float r = keep + __shfl_xor(send, 4);
    r += __shfl_xor(r, 2);
    r += __shfl_xor(r, 1);
    return r;
}

// 8 partials -> totals; lane L gets token (L>>3)
__device__ __forceinline__ float reduce8(const float* v, int lane) {
    float r4[4];
    #pragma unroll
    for (int i = 0; i < 4; ++i) {
        bool hi = lane & 32;
        float keep = hi ? v[i + 4] : v[i];
        float send = hi ? v[i] : v[i + 4];
        r4[i] = keep + __shfl_xor(send, 32);
    }
    float r2[2];
    #pragma unroll
    for (int i = 0; i < 2; ++i) {
        bool hi = lane & 16;
        float keep = hi ? r4[i + 2] : r4[i];
        float send = hi ? r4[i] : r4[i + 2];
        r2[i] = keep + __shfl_xor(send, 16);
    }
    bool hi = lane & 8;
    float keep = hi ? r2[1] : r2[0];
    float send = hi ? r2[0] : r2[1];
    float r = keep + __shfl_xor(send, 8);
    r += __shfl_xor(r, 4);
    r += __shfl_xor(r, 2);
    r += __shfl_xor(r, 1);
    return r;
}

__global__ void routing_kernel(const float* __restrict__ x, const float* __restrict__ rw,
                               int* __restrict__ top_idx, float* __restrict__ top_w) {
    int t = blockIdx.x;
    int tid = threadIdx.x;          // 256
    int e = tid >> 4, seg = tid & 15;
    const float* xr = x + t * HD + seg * 64;
    const float* wr = rw + e * HD + seg * 64;
    float p = 0.f;
    #pragma unroll 8
    for (int i = 0; i < 64; ++i) p += xr[i] * wr[i];
    __shared__ float part[16][16];
    __shared__ float logit[16];
    part[e][seg] = p;
    __syncthreads();
    if (tid < 16) {
        float s = 0.f;
        #pragma unroll
        for (int i = 0; i < 16; ++i) s += part[tid][i];
        logit[tid] = s;
    }
    __syncthreads();
    if (tid == 0) {
        int i0 = 0; float v0 = logit[0];
        #pragma unroll
        for (int i = 1; i < 16; ++i) { if (logit[i] > v0) { v0 = logit[i]; i0 = i; } }
        int i1 = -1; float v1 = -1e30f;
        #pragma unroll
        for (int i = 0; i < 16; ++i) { if (i != i0 && logit[i] > v1) { v1 = logit[i]; i1 = i; } }
        float w0 = 1.f / (1.f + expf(v1 - v0));
        float w1 = 1.f / (1.f + expf(v0 - v1));
        top_idx[t * 2]     = i0;  top_w[t * 2]     = w0;
        top_idx[t * 2 + 1] = i1;  top_w[t * 2 + 1] = w1;
    }
}

__global__ void build_kernel(const int* __restrict__ top_idx,
                             int* __restrict__ cnt, int* __restrict__ pref,
                             int* __restrict__ slot, int* __restrict__ invtok,
                             int* __restrict__ meta, int* __restrict__ tl1,
                             int* __restrict__ tl2) {
    __shared__ int scnt[16], spref[16], scur[16];
    int tid = threadIdx.x;          // 256
    if (tid < 16) scnt[tid] = 0;
    __syncthreads();
    int e = top_idx[tid];
    atomicAdd(&scnt[e], 1);
    __syncthreads();
    if (tid == 0) {
        int s = 0;
        for (int i = 0; i < 16; ++i) { spref[i] = s; pref[i] = s; cnt[i] = scnt[i]; s += scnt[i]; }
        int m1 = 0, m2 = 0;
        for (int i = 0; i < 16; ++i) {
            int ntile1 = (scnt[i] + 15) >> 4;
            for (int m = 0; m < ntile1; ++m) tl1[m1++] = (i << 8) | m;
            int ntile2 = (scnt[i] + 7) >> 3;
            for (int m = 0; m < ntile2; ++m) tl2[m2++] = (i << 8) | m;
        }
        meta[0] = m1;
        meta[1] = m2;
    }
    if (tid < 16) scur[tid] = 0;
    __syncthreads();
    int pos = spref[e] + atomicAdd(&scur[e], 1);
    slot[tid] = pos;
    invtok[pos] = tid >> 1;
}

__global__ void gather_kernel(const float* __restrict__ x, const int* __restrict__ invtok,
                              _Float16* __restrict__ xh) {
    int slt = blockIdx.x;           // 256
    int t = invtok[slt];
    int i = threadIdx.x;            // 256 threads x 4 elems
    float4 v = ((const float4*)(x + (long)t * HD))[i];
    union { _Float16 h[4]; int2 p; } o;
    o.h[0] = (_Float16)v.x; o.h[1] = (_Float16)v.y;
    o.h[2] = (_Float16)v.z; o.h[3] = (_Float16)v.w;
    ((int2*)(xh + (long)slt * HD))[i] = o.p;
}

// gu GEMM + SwiGLU. x tile (16 tokens) in LDS; weights decoded once per f-row;
// tokens inner. Bank-uniform pairing swizzle via b=(lane>>2)&1 applied to BOTH
// x LDS reads and weight global reads (sum is pairing-invariant).
__global__ __launch_bounds__(256, 4) void gemm1_lds(
    const _Float16* __restrict__ xh, const int* __restrict__ qblk,
    const int* __restrict__ qscl, const float* __restrict__ bias,
    const int* __restrict__ meta, const int* __restrict__ tl1,
    const int* __restrict__ cnt, const int* __restrict__ pref,
    _Float16* __restrict__ hbuf) {
    __shared__ int lut[256];
    __shared__ int4 xs4[2048];          // 16 tokens x 128 int4 (32 KB)
    int tid = threadIdx.x;
    lut[tid] = fp4h(tid & 15) | (fp4h(tid >> 4) << 16);
    int wave = tid >> 6, lane = tid & 63;
    int b = (lane >> 2) & 1;
    int i0 = 2 * lane + b;
    int i1 = 2 * lane + 1 - b;
    int nwork = meta[0] << 6;

    for (int w = blockIdx.x; w < nwork; w += gridDim.x) {
        int tile = tl1[w >> 6];
        int fblk = w & 63;
        int e = tile >> 8;
        int mt = tile & 255;
        int n = cnt[e];
        int nt = n - mt * 16; if (nt > 16) nt = 16;
        int base = pref[e];
        int t0 = base + mt * 16;

        __syncthreads();
        const int4* xg4 = (const int4*)xh;
        for (int j = tid; j < 2048; j += 256) {
            int trow = j >> 7;
            int tt = trow < nt ? trow : nt - 1;
            xs4[j] = xg4[(long)(t0 + tt) * 128 + (j & 127)];
        }
        __syncthreads();

        int f0 = fblk * 32 + wave * 8;
        long rg0 = (long)e * 4096 + f0;

        for (int fi = 0; fi < 8; ++fi) {
            long rg = rg0 + fi;            // gate row
            long ru = rg + FD;             // up row
            const int4* wpg = (const int4*)(qblk + rg * 512);
            const int4* wpu = (const int4*)(qblk + ru * 512);
            int4 G0 = wpg[i0], G1 = wpg[i1];
            int4 U0 = wpu[i0], U1 = wpu[i1];
            int scg = qscl[rg * 32 + (lane >> 1)];
            int svg = (scg - 112) << 10; svg |= svg << 16;
            int scu = qscl[ru * 32 + (lane >> 1)];
            int svu = (scu - 112) << 10; svu |= svu << 16;

            half2v wg[8], wu[8];
            wg[0] = dec2(lut, G0.x, svg); wg[1] = dec2(lut, G0.y, svg);
            wg[2] = dec2(lut, G0.z, svg); wg[3] = dec2(lut, G0.w, svg);
            wg[4] = dec2(lut, G1.x, svg); wg[5] = dec2(lut, G1.y, svg);
            wg[6] = dec2(lut, G1.z, svg); wg[7] = dec2(lut, G1.w, svg);
            wu[0] = dec2(lut, U0.x, svu); wu[1] = dec2(lut, U0.y, svu);
            wu[2] = dec2(lut, U0.z, svu); wu[3] = dec2(lut, U0.w, svu);
            wu[4] = dec2(lut, U1.x, svu); wu[5] = dec2(lut, U1.y, svu);
            wu[6] = dec2(lut, U1.z, svu); wu[7] = dec2(lut, U1.w, svu);

            float accg[16], accu[16];
            #pragma unroll
            for (int t = 0; t < 16; ++t) {
                XF xa, xb;
                xa.v = xs4[t * 128 + i0];
                xb.v = xs4[t * 128 + i1];
                float a = 0.f, bb = 0.f;
                #pragma unroll
                for (int i = 0; i < 4; ++i) {
                    a  = FDOT2(wg[i],     xa.h[i], a);
                    a  = FDOT2(wg[i + 4], xb.h[i], a);
                    bb = FDOT2(wu[i],     xa.h[i], bb);
                    bb = FDOT2(wu[i + 4], xb.h[i], bb);
                }
                accg[t] = a;
                accu[t] = bb;
            }
            float rgv = reduce16(accg, lane);
            float ruv = reduce16(accu, lane);
            if ((lane & 3) == 0) {
                int t = lane >> 2;
                if (t < nt) {
                    float g = rgv + bias[rg];
                    float u = ruv + bias[ru];
                    float h = (g / (1.f + expf(-g))) * u;
                    hbuf[(long)(t0 + t) * FD + f0 + fi] = (_Float16)(h * 0.0625f);  // 2^-4
                }
            }
        }
    }
}

// down GEMM. h tile (8 tokens) in LDS; weights decoded once per h-row; tokens inner.
// Bank-uniform swizzle: j-th int4 of lane's slice at index 4*lane + (j ^ ((lane>>1)&3)),
// applied to BOTH LDS x reads and global weight reads.
__global__ __launch_bounds__(256, 4) void gemm2_lds(
    const _Float16* __restrict__ hbuf, const int* __restrict__ qblk,
    const int* __restrict__ qscl, const float* __restrict__ bias,
    const int* __restrict__ meta, const int* __restrict__ tl2,
    const int* __restrict__ cnt, const int* __restrict__ pref,
    float* __restrict__ y) {
    __shared__ int lut[256];
    __shared__ int4 hs4[2048];          // 8 tokens x 256 int4 (32 KB)
    int tid = threadIdx.x;
    lut[tid] = fp4h(tid & 15) | (fp4h(tid >> 4) << 16);
    int wave = tid >> 6, lane = tid & 63;
    int c = (lane >> 1) & 3;
    int ix[4];
    #pragma unroll
    for (int j = 0; j < 4; ++j) ix[j] = 4 * lane + (j ^ c);
    int nwork = meta[1] << 5;

    for (int w = blockIdx.x; w < nwork; w += gridDim.x) {
        int tile = tl2[w >> 5];
        int hblk = w & 31;
        int e = tile >> 8;
        int mt = tile & 255;
        int n = cnt[e];
        int nt = n - mt * 8; if (nt > 8) nt = 8;
        int base = pref[e];
        int t0 = base + mt * 8;

        __syncthreads();
        const int4* hg4 = (const int4*)hbuf;
        for (int j = tid; j < 2048; j += 256) {
            int trow = j >> 8;
            int tt = trow < nt ? trow : nt - 1;
            hs4[j] = hg4[(long)(t0 + tt) * 256 + (j & 255)];
        }
        __syncthreads();

        int h0 = hblk * 32 + wave * 8;
        long r0 = (long)e * HD + h0;

        for (int hi = 0; hi < 8; ++hi) {
            long r = r0 + hi;
            const int4* wp = (const int4*)(qblk + r * 1024);
            int4 Q0 = wp[ix[0]], Q1 = wp[ix[1]], Q2 = wp[ix[2]], Q3 = wp[ix[3]];
            int sc = qscl[r * 64 + lane];
            int sv = (sc - 112) << 10; sv |= sv << 16;

            half2v wv[16];
            wv[0]  = dec2(lut, Q0.x, sv); wv[1]  = dec2(lut, Q0.y, sv);
            wv[2]  = dec2(lut, Q0.z, sv); wv[3]  = dec2(lut, Q0.w, sv);
            wv[4]  = dec2(lut, Q1.x, sv); wv[5]  = dec2(lut, Q1.y, sv);
            wv[6]  = dec2(lut, Q1.z, sv); wv[7]  = dec2(lut, Q1.w, sv);
            wv[8]  = dec2(lut, Q2.x, sv); wv[9]  = dec2(lut, Q2.y, sv);
            wv[10] = dec2(lut, Q2.z, sv); wv[11] = dec2(lut, Q2.w, sv);
            wv[12] = dec2(lut, Q3.x, sv); wv[13] = dec2(lut, Q3.y, sv);
            wv[14] = dec2(lut, Q3.z, sv); wv[15] = dec2(lut, Q3.w, sv);

            float acc[8];
            #pragma unroll
            for (int t = 0; t < 8; ++t) {
                float a = 0.f;
                #pragma unroll
                for (int j = 0; j < 4; ++j) {
                    XF xq;
                    xq.v = hs4[t * 256 + ix[j]];
                    a = FDOT2(wv[j * 4 + 0], xq.h[0], a);
                    a = FDOT2(wv[j * 4 + 1], xq.h[1], a);
                    a = FDOT2(wv[j * 4 + 2], xq.h[2], a);
                    a = FDOT2(wv[j * 4 + 3], xq.h[3], a);
                }
                acc[t] = a;
            }
            float rv = reduce8(acc, lane);
            if ((lane & 7) == 0) {
                int t = lane >> 3;
                if (t < nt)
                    y[(long)(t0 + t) * HD + h0 + hi] = rv * 16.f + bias[r];
            }
        }
    }
}

__global__ void combine_kernel(const float* __restrict__ ybuf, const int* __restrict__ slot,
                               const float* __restrict__ topw, float* __restrict__ out) {
    int t = blockIdx.x;
    int i = threadIdx.x;   // 256, float4 each
    int s0 = slot[2 * t], s1 = slot[2 * t + 1];
    float w0 = topw[2 * t], w1 = topw[2 * t + 1];
    float4 a = ((const float4*)(ybuf + (long)s0 * HD))[i];
    float4 b = ((const float4*)(ybuf + (long)s1 * HD))[i];
    float4 o;
    o.x = w0 * a.x + w1 * b.x;
    o.y = w0 * a.y + w1 * b.y;
    o.z = w0 * a.z + w1 * b.z;
    o.w = w0 * a.w + w1 * b.w;
    ((float4*)(out + (long)t * HD))[i] = o;
}

extern "C" void kernel_launch(void* const* d_in, const int* in_sizes, int n_in,
                              void* d_out, int out_size, void* d_ws, size_t ws_size,
                              hipStream_t stream) {
    const float* x          = (const float*)d_in[0];
    const float* rw         = (const float*)d_in[1];
    const float* bias_gu    = (const float*)d_in[2];
    const float* bias_down  = (const float*)d_in[3];
    const int*   blocks_gu  = (const int*)d_in[4];
    const int*   scales_gu  = (const int*)d_in[5];
    const int*   blocks_down= (const int*)d_in[6];
    const int*   scales_down= (const int*)d_in[7];
    float* out = (float*)d_out;
    int*   wsI = (int*)d_ws;
    float* wsF = (float*)d_ws;
    _Float16* xh   = (_Float16*)(wsI + XH_OFF);
    _Float16* hbuf = (_Float16*)(wsI + HBUF_OFF);
    float*    y    = wsF + Y_OFF;

    routing_kernel<<<128, 256, 0, stream>>>(x, rw, wsI + TOPI_OFF, wsF + TOPW_OFF);
    build_kernel<<<1, 256, 0, stream>>>(wsI + TOPI_OFF, wsI + CNT_OFF, wsI + PREF_OFF,
                                        wsI + SLOT_OFF, wsI + INVT_OFF,
                                        wsI + META_OFF, wsI + TL1_OFF, wsI + TL2_OFF);
    gather_kernel<<<256, 256, 0, stream>>>(x, wsI + INVT_OFF, xh);
    gemm1_lds<<<1280, 256, 0, stream>>>(xh, blocks_gu, scales_gu, bias_gu,
                                        wsI + META_OFF, wsI + TL1_OFF,
                                        wsI + CNT_OFF, wsI + PREF_OFF, hbuf);
    gemm2_lds<<<1280, 256, 0, stream>>>(hbuf, blocks_down, scales_down, bias_down,
                                        wsI + META_OFF, wsI + TL2_OFF,
                                        wsI + CNT_OFF, wsI + PREF_OFF, y);
    combine_kernel<<<128, 256, 0, stream>>>(y, wsI + SLOT_OFF, wsF + TOPW_OFF, out);
}

// Round 14
// 67.930 us; speedup vs baseline: 5.2907x; 5.2907x over previous
//
#include <hip/hip_runtime.h>
#include <hip/hip_fp16.h>
#include <math.h>

#define NE 16
#define HD 1024
#define FD 2048

typedef _Float16 half8 __attribute__((ext_vector_type(8)));
typedef float f32x4 __attribute__((ext_vector_type(4)));

// ws layout (4-byte units)
#define TOPI_OFF 0          // 256 int
#define TOPW_OFF 256        // 256 float
#define CNT_OFF  512        // 16 int
#define PREF_OFF 528        // 16 int
#define SLOT_OFF 544        // 256 int (pair -> slot)
#define INVT_OFF 800        // 256 int (slot -> token)
#define META_OFF 1056       // 1 int: M1
#define TL1_OFF  1060       // 64 int  (e<<8|mt) 16-token tiles
#define XH_OFF   4096                   // xh fp16 [256][1024] = 131072 ints
#define HBUF_OFF (XH_OFF + 131072)      // h  fp16 [256][2048] = 262144 ints
#define Y_OFF    (HBUF_OFF + 262144)    // y  f32  [256][1024] = 262144 ints

union XI { int4 v; half8 h; };

// fp4 e2m1 nibble -> fp16 bits (unscaled)
__device__ __forceinline__ int fp4h(int nib) {
    int c = nib & 7;
    int v;
    if (c == 0) v = 0;
    else if (c == 1) v = 14 << 10;                        // 0.5
    else v = (((c >> 1) + 14) << 10) | ((c & 1) << 9);
    v |= (nib & 8) << 12;
    return v;
}

// LUT byte -> 2 packed fp16 times packed pow2 scale (exact)
__device__ __forceinline__ int dec2i(const int* lut, int byte, int sv) {
    int l = lut[byte & 255];
    __half2 p = *reinterpret_cast<const __half2*>(&l);
    __half2 sc = *reinterpret_cast<const __half2*>(&sv);
    __half2 r = __hmul2(p, sc);
    return *reinterpret_cast<int*>(&r);
}

__global__ void routing_kernel(const float* __restrict__ x, const float* __restrict__ rw,
                               int* __restrict__ top_idx, float* __restrict__ top_w) {
    int t = blockIdx.x;
    int tid = threadIdx.x;          // 256
    int e = tid >> 4, seg = tid & 15;
    const float* xr = x + t * HD + seg * 64;
    const float* wr = rw + e * HD + seg * 64;
    float p = 0.f;
    #pragma unroll 8
    for (int i = 0; i < 64; ++i) p += xr[i] * wr[i];
    __shared__ float part[16][16];
    __shared__ float logit[16];
    part[e][seg] = p;
    __syncthreads();
    if (tid < 16) {
        float s = 0.f;
        #pragma unroll
        for (int i = 0; i < 16; ++i) s += part[tid][i];
        logit[tid] = s;
    }
    __syncthreads();
    if (tid == 0) {
        int i0 = 0; float v0 = logit[0];
        #pragma unroll
        for (int i = 1; i < 16; ++i) { if (logit[i] > v0) { v0 = logit[i]; i0 = i; } }
        int i1 = -1; float v1 = -1e30f;
        #pragma unroll
        for (int i = 0; i < 16; ++i) { if (i != i0 && logit[i] > v1) { v1 = logit[i]; i1 = i; } }
        float w0 = 1.f / (1.f + expf(v1 - v0));
        float w1 = 1.f / (1.f + expf(v0 - v1));
        top_idx[t * 2]     = i0;  top_w[t * 2]     = w0;
        top_idx[t * 2 + 1] = i1;  top_w[t * 2 + 1] = w1;
    }
}

__global__ void build_kernel(const int* __restrict__ top_idx,
                             int* __restrict__ cnt, int* __restrict__ pref,
                             int* __restrict__ slot, int* __restrict__ invtok,
                             int* __restrict__ meta, int* __restrict__ tl1) {
    __shared__ int scnt[16], spref[16], scur[16];
    int tid = threadIdx.x;          // 256
    if (tid < 16) scnt[tid] = 0;
    __syncthreads();
    int e = top_idx[tid];
    atomicAdd(&scnt[e], 1);
    __syncthreads();
    if (tid == 0) {
        int s = 0;
        for (int i = 0; i < 16; ++i) { spref[i] = s; pref[i] = s; cnt[i] = scnt[i]; s += scnt[i]; }
        int m1 = 0;
        for (int i = 0; i < 16; ++i) {
            int ntile1 = (scnt[i] + 15) >> 4;
            for (int m = 0; m < ntile1; ++m) tl1[m1++] = (i << 8) | m;
        }
        meta[0] = m1;
    }
    if (tid < 16) scur[tid] = 0;
    __syncthreads();
    int pos = spref[e] + atomicAdd(&scur[e], 1);
    slot[tid] = pos;
    invtok[pos] = tid >> 1;
}

__global__ void gather_kernel(const float* __restrict__ x, const int* __restrict__ invtok,
                              _Float16* __restrict__ xh) {
    int slt = blockIdx.x;           // 256
    int t = invtok[slt];
    int i = threadIdx.x;            // 256 threads x 4 elems
    float4 v = ((const float4*)(x + (long)t * HD))[i];
    union { _Float16 h[4]; int2 p; } o;
    o.h[0] = (_Float16)v.x; o.h[1] = (_Float16)v.y;
    o.h[2] = (_Float16)v.z; o.h[3] = (_Float16)v.w;
    ((int2*)(xh + (long)slt * HD))[i] = o.p;
}

// gu GEMM + SwiGLU, canonical MFMA + LDS staging.
// Block = (16-token tile, 32-f chunk of 64). B-tile = 64 rows (32 gate + 32 up), BK=64.
// Wave w owns B rows w*16..w*16+15 (w0,w1: gate; w2,w3: up).
__global__ __launch_bounds__(256) void gemm1_mfma(
    const _Float16* __restrict__ xh, const int* __restrict__ qblk,
    const int* __restrict__ qscl, const float* __restrict__ bias,
    const int* __restrict__ cnt, const int* __restrict__ pref,
    const int* __restrict__ meta, const int* __restrict__ tl1,
    _Float16* __restrict__ hbuf) {
    __shared__ int lut[256];
    __shared__ int4 Asb[128];           // 16 tok x 8 int4 (swizzled), 2 KB
    __shared__ int4 Bsb[512];           // 64 rows x 8 int4 (swizzled), 8 KB
    __shared__ float exch[4][64][4];    // 4 KB
    int tid = threadIdx.x;
    lut[tid] = fp4h(tid & 15) | (fp4h(tid >> 4) << 16);
    int wave = tid >> 6, lane = tid & 63;
    int bl = lane & 15, kb4 = lane >> 4;
    int rloc = wave * 16 + bl;          // this lane's B row for MFMA frag
    int rs = tid >> 2, kq = tid & 3;    // staging: row, k-quarter
    int tok = tid >> 3, ga = tid & 7;   // A staging (tid<128)
    int nwork = meta[0] << 6;           // 64 f-chunks of 32

    for (int w = blockIdx.x; w < nwork; w += gridDim.x) {
        int tile = tl1[w >> 6];
        int fc = w & 63;
        int e = tile >> 8, mt = tile & 255;
        int n = cnt[e];
        int nt = n - mt * 16; if (nt > 16) nt = 16;
        int base = pref[e];
        int t0 = base + mt * 16;
        int f0 = fc * 32;

        long rowg = (long)e * 4096 + ((rs < 32) ? (f0 + rs) : (2048 + f0 + rs - 32));
        const int4* wrow = (const int4*)(qblk + rowg * 512);
        const int* srow = qscl + rowg * 32;
        int tclamp = (tok < nt) ? tok : nt - 1;
        const int4* arow = (const int4*)xh + (long)(t0 + tclamp) * 128;

        f32x4 acc = {0.f, 0.f, 0.f, 0.f};
        for (int kb = 0; kb < 16; ++kb) {
            __syncthreads();
            if (tid < 128)
                Asb[tok * 8 + (ga ^ (tok & 7))] = arow[kb * 8 + ga];
            {
                int4 q0 = wrow[kb * 8 + kq * 2];
                int4 q1 = wrow[kb * 8 + kq * 2 + 1];
                int sc = srow[kb * 2 + (kq >> 1)];
                int sv = (sc - 112) << 10; sv |= sv << 16;
                int4 o0, o1;
                o0.x = dec2i(lut, q0.x, sv); o0.y = dec2i(lut, q0.y, sv);
                o0.z = dec2i(lut, q0.z, sv); o0.w = dec2i(lut, q0.w, sv);
                o1.x = dec2i(lut, q1.x, sv); o1.y = dec2i(lut, q1.y, sv);
                o1.z = dec2i(lut, q1.z, sv); o1.w = dec2i(lut, q1.w, sv);
                Bsb[rs * 8 + ((kq * 2) ^ (rs & 7))] = o0;
                Bsb[rs * 8 + ((kq * 2 + 1) ^ (rs & 7))] = o1;
            }
            __syncthreads();
            #pragma unroll
            for (int ks = 0; ks < 2; ++ks) {
                int g = ks * 4 + kb4;
                XI a, b;
                a.v = Asb[bl * 8 + (g ^ (bl & 7))];
                b.v = Bsb[rloc * 8 + (g ^ (rloc & 7))];
                acc = __builtin_amdgcn_mfma_f32_16x16x32_f16(a.h, b.h, acc, 0, 0, 0);
            }
        }
        #pragma unroll
        for (int i = 0; i < 4; ++i) exch[wave][lane][i] = acc[i];
        __syncthreads();
        // epilogue: 16 tok x 32 f; thread: fl = tid&31, toks tid>>5 and +8
        int fl = tid & 31, wv = fl >> 4, col = fl & 15;
        float bg = bias[(long)e * 4096 + f0 + fl];
        float bu = bias[(long)e * 4096 + 2048 + f0 + fl];
        #pragma unroll
        for (int d = 0; d < 2; ++d) {
            int tk = (tid >> 5) + d * 8;
            int ln = ((tk >> 2) << 4) | col;
            int rg = tk & 3;
            float g = exch[wv][ln][rg] + bg;
            float u = exch[wv + 2][ln][rg] + bu;
            float h = (g / (1.f + expf(-g))) * u;
            if (tk < nt)
                hbuf[(long)(t0 + tk) * FD + f0 + fl] = (_Float16)(h * 0.0625f);  // 2^-4
        }
    }
}

// down GEMM, MFMA + LDS staging, K split in 2 halves; both halves atomicAdd into y
// (two-operand fp add is commutative -> deterministic). y zeroed at launch.
__global__ __launch_bounds__(256) void gemm2_mfma(
    const _Float16* __restrict__ hbuf, const int* __restrict__ qblk,
    const int* __restrict__ qscl, const float* __restrict__ bias,
    const int* __restrict__ cnt, const int* __restrict__ pref,
    const int* __restrict__ meta, const int* __restrict__ tl1,
    float* __restrict__ y) {
    __shared__ int lut[256];
    __shared__ int4 Asb[128];
    __shared__ int4 Bsb[512];
    int tid = threadIdx.x;
    lut[tid] = fp4h(tid & 15) | (fp4h(tid >> 4) << 16);
    int wave = tid >> 6, lane = tid & 63;
    int bl = lane & 15, kb4 = lane >> 4;
    int rloc = wave * 16 + bl;
    int rs = tid >> 2, kq = tid & 3;
    int tok = tid >> 3, ga = tid & 7;
    int nwork = meta[0] << 5;           // 16 h-chunks x 2 k-halves

    for (int w = blockIdx.x; w < nwork; w += gridDim.x) {
        int tile = tl1[w >> 5];
        int sub = w & 31;
        int hc = sub & 15, kh = sub >> 4;
        int e = tile >> 8, mt = tile & 255;
        int n = cnt[e];
        int nt = n - mt * 16; if (nt > 16) nt = 16;
        int base = pref[e];
        int t0 = base + mt * 16;
        int h0 = hc * 64;

        long rowg = (long)e * HD + h0 + rs;
        const int4* wrow = (const int4*)(qblk + rowg * 1024);
        const int* srow = qscl + rowg * 64;
        int tclamp = (tok < nt) ? tok : nt - 1;
        const int4* arow = (const int4*)hbuf + (long)(t0 + tclamp) * 256;
        int kb0 = kh * 16;

        f32x4 acc = {0.f, 0.f, 0.f, 0.f};
        for (int kb = 0; kb < 16; ++kb) {
            int kbb = kb0 + kb;
            __syncthreads();
            if (tid < 128)
                Asb[tok * 8 + (ga ^ (tok & 7))] = arow[kbb * 8 + ga];
            {
                int4 q0 = wrow[kbb * 8 + kq * 2];
                int4 q1 = wrow[kbb * 8 + kq * 2 + 1];
                int sc = srow[kbb * 2 + (kq >> 1)];
                int sv = (sc - 112) << 10; sv |= sv << 16;
                int4 o0, o1;
                o0.x = dec2i(lut, q0.x, sv); o0.y = dec2i(lut, q0.y, sv);
                o0.z = dec2i(lut, q0.z, sv); o0.w = dec2i(lut, q0.w, sv);
                o1.x = dec2i(lut, q1.x, sv); o1.y = dec2i(lut, q1.y, sv);
                o1.z = dec2i(lut, q1.z, sv); o1.w = dec2i(lut, q1.w, sv);
                Bsb[rs * 8 + ((kq * 2) ^ (rs & 7))] = o0;
                Bsb[rs * 8 + ((kq * 2 + 1) ^ (rs & 7))] = o1;
            }
            __syncthreads();
            #pragma unroll
            for (int ks = 0; ks < 2; ++ks) {
                int g = ks * 4 + kb4;
                XI a, b;
                a.v = Asb[bl * 8 + (g ^ (bl & 7))];
                b.v = Bsb[rloc * 8 + (g ^ (rloc & 7))];
                acc = __builtin_amdgcn_mfma_f32_16x16x32_f16(a.h, b.h, acc, 0, 0, 0);
            }
        }
        // C: col=lane&15 -> h row; row=(lane>>4)*4+reg -> token
        int hcol = h0 + wave * 16 + bl;
        float bv = (kh == 0) ? bias[(long)e * HD + hcol] : 0.f;
        #pragma unroll
        for (int r = 0; r < 4; ++r) {
            int row = kb4 * 4 + r;
            if (row < nt)
                atomicAdd(&y[(long)(t0 + row) * HD + hcol], acc[r] * 16.f + bv);
        }
    }
}

__global__ void combine_kernel(const float* __restrict__ y, const int* __restrict__ slot,
                               const float* __restrict__ topw, float* __restrict__ out) {
    int t = blockIdx.x;
    int i = threadIdx.x;   // 256, float4 each
    int s0 = slot[2 * t], s1 = slot[2 * t + 1];
    float w0 = topw[2 * t], w1 = topw[2 * t + 1];
    float4 a = ((const float4*)(y + (long)s0 * HD))[i];
    float4 b = ((const float4*)(y + (long)s1 * HD))[i];
    float4 o;
    o.x = w0 * a.x + w1 * b.x;
    o.y = w0 * a.y + w1 * b.y;
    o.z = w0 * a.z + w1 * b.z;
    o.w = w0 * a.w + w1 * b.w;
    ((float4*)(out + (long)t * HD))[i] = o;
}

extern "C" void kernel_launch(void* const* d_in, const int* in_sizes, int n_in,
                              void* d_out, int out_size, void* d_ws, size_t ws_size,
                              hipStream_t stream) {
    const float* x          = (const float*)d_in[0];
    const float* rw         = (const float*)d_in[1];
    const float* bias_gu    = (const float*)d_in[2];
    const float* bias_down  = (const float*)d_in[3];
    const int*   blocks_gu  = (const int*)d_in[4];
    const int*   scales_gu  = (const int*)d_in[5];
    const int*   blocks_down= (const int*)d_in[6];
    const int*   scales_down= (const int*)d_in[7];
    float* out = (float*)d_out;
    int*   wsI = (int*)d_ws;
    float* wsF = (float*)d_ws;
    _Float16* xh   = (_Float16*)(wsI + XH_OFF);
    _Float16* hbuf = (_Float16*)(wsI + HBUF_OFF);
    float*    y    = wsF + Y_OFF;

    (void)hipMemsetAsync(y, 0, 256 * HD * sizeof(float), stream);
    routing_kernel<<<128, 256, 0, stream>>>(x, rw, wsI + TOPI_OFF, wsF + TOPW_OFF);
    build_kernel<<<1, 256, 0, stream>>>(wsI + TOPI_OFF, wsI + CNT_OFF, wsI + PREF_OFF,
                                        wsI + SLOT_OFF, wsI + INVT_OFF,
                                        wsI + META_OFF, wsI + TL1_OFF);
    gather_kernel<<<256, 256, 0, stream>>>(x, wsI + INVT_OFF, xh);
    gemm1_mfma<<<2048, 256, 0, stream>>>(xh, blocks_gu, scales_gu, bias_gu,
                                         wsI + CNT_OFF, wsI + PREF_OFF,
                                         wsI + META_OFF, wsI + TL1_OFF, hbuf);
    gemm2_mfma<<<1024, 256, 0, stream>>>(hbuf, blocks_down, scales_down, bias_down,
                                         wsI + CNT_OFF, wsI + PREF_OFF,
                                         wsI + META_OFF, wsI + TL1_OFF, y);
    combine_kernel<<<128, 256, 0, stream>>>(y, wsI + SLOT_OFF, wsF + TOPW_OFF, out);
}

// Round 15
// 60.873 us; speedup vs baseline: 5.9041x; 1.1159x over previous
//
#include <hip/hip_runtime.h>
#include <hip/hip_fp16.h>
#include <math.h>

#define NE 16
#define HD 1024
#define FD 2048

typedef _Float16 half8 __attribute__((ext_vector_type(8)));
typedef float f32x4 __attribute__((ext_vector_type(4)));

// ws layout (4-byte units) — ws is ~512 MB (poison fill observed), plenty.
#define TOPI_OFF 0          // 256 int
#define TOPW_OFF 256        // 256 float
#define CNT_OFF  512        // 16 int
#define PREF_OFF 528        // 16 int
#define SLOT_OFF 544        // 256 int (pair -> slot)
#define INVT_OFF 800        // 256 int (slot -> token)
#define META_OFF 1056       // 1 int: M1
#define TL1_OFF  1060       // 64 int  (e<<8|mt) 16-token tiles
#define XH_OFF   4096                   // xh fp16 [256][1024] = 131072 ints
#define HBUF_OFF (XH_OFF + 131072)      // h  fp16 [256][2048] = 262144 ints
#define Y0_OFF   (HBUF_OFF + 262144)    // y0 f32 [256][1024]
#define Y1_OFF   (Y0_OFF + 262144)      // y1 f32 [256][1024]

union XI { int4 v; half8 h; };

// fp4 e2m1 nibble -> fp16 bits (unscaled)
__device__ __forceinline__ int fp4h(int nib) {
    int c = nib & 7;
    int v;
    if (c == 0) v = 0;
    else if (c == 1) v = 14 << 10;                        // 0.5
    else v = (((c >> 1) + 14) << 10) | ((c & 1) << 9);
    v |= (nib & 8) << 12;
    return v;
}

// LUT byte -> 2 packed fp16 times packed pow2 scale (exact)
__device__ __forceinline__ int dec2i(const int* lut, int byte, int sv) {
    int l = lut[byte & 255];
    __half2 p = *reinterpret_cast<const __half2*>(&l);
    __half2 sc = *reinterpret_cast<const __half2*>(&sv);
    __half2 r = __hmul2(p, sc);
    return *reinterpret_cast<int*>(&r);
}

__global__ void routing_kernel(const float* __restrict__ x, const float* __restrict__ rw,
                               int* __restrict__ top_idx, float* __restrict__ top_w) {
    int t = blockIdx.x;
    int tid = threadIdx.x;          // 256
    int e = tid >> 4, seg = tid & 15;
    const float* xr = x + t * HD + seg * 64;
    const float* wr = rw + e * HD + seg * 64;
    float p = 0.f;
    #pragma unroll 8
    for (int i = 0; i < 64; ++i) p += xr[i] * wr[i];
    __shared__ float part[16][16];
    __shared__ float logit[16];
    part[e][seg] = p;
    __syncthreads();
    if (tid < 16) {
        float s = 0.f;
        #pragma unroll
        for (int i = 0; i < 16; ++i) s += part[tid][i];
        logit[tid] = s;
    }
    __syncthreads();
    if (tid == 0) {
        int i0 = 0; float v0 = logit[0];
        #pragma unroll
        for (int i = 1; i < 16; ++i) { if (logit[i] > v0) { v0 = logit[i]; i0 = i; } }
        int i1 = -1; float v1 = -1e30f;
        #pragma unroll
        for (int i = 0; i < 16; ++i) { if (i != i0 && logit[i] > v1) { v1 = logit[i]; i1 = i; } }
        float w0 = 1.f / (1.f + expf(v1 - v0));
        float w1 = 1.f / (1.f + expf(v0 - v1));
        top_idx[t * 2]     = i0;  top_w[t * 2]     = w0;
        top_idx[t * 2 + 1] = i1;  top_w[t * 2 + 1] = w1;
    }
}

__global__ void build_kernel(const int* __restrict__ top_idx,
                             int* __restrict__ cnt, int* __restrict__ pref,
                             int* __restrict__ slot, int* __restrict__ invtok,
                             int* __restrict__ meta, int* __restrict__ tl1) {
    __shared__ int scnt[16], spref[16], scur[16];
    int tid = threadIdx.x;          // 256
    if (tid < 16) scnt[tid] = 0;
    __syncthreads();
    int e = top_idx[tid];
    atomicAdd(&scnt[e], 1);
    __syncthreads();
    if (tid == 0) {
        int s = 0;
        for (int i = 0; i < 16; ++i) { spref[i] = s; pref[i] = s; cnt[i] = scnt[i]; s += scnt[i]; }
        int m1 = 0;
        for (int i = 0; i < 16; ++i) {
            int ntile1 = (scnt[i] + 15) >> 4;
            for (int m = 0; m < ntile1; ++m) tl1[m1++] = (i << 8) | m;
        }
        meta[0] = m1;
    }
    if (tid < 16) scur[tid] = 0;
    __syncthreads();
    int pos = spref[e] + atomicAdd(&scur[e], 1);
    slot[tid] = pos;
    invtok[pos] = tid >> 1;
}

__global__ void gather_kernel(const float* __restrict__ x, const int* __restrict__ invtok,
                              _Float16* __restrict__ xh) {
    int slt = blockIdx.x;           // 256
    int t = invtok[slt];
    int i = threadIdx.x;            // 256 threads x 4 elems
    float4 v = ((const float4*)(x + (long)t * HD))[i];
    union { _Float16 h[4]; int2 p; } o;
    o.h[0] = (_Float16)v.x; o.h[1] = (_Float16)v.y;
    o.h[2] = (_Float16)v.z; o.h[3] = (_Float16)v.w;
    ((int2*)(xh + (long)slt * HD))[i] = o.p;
}

// gu GEMM + SwiGLU: MFMA, double-buffered LDS, prefetch-pipelined staging.
// Block = (16-token tile, 32-f chunk of 64). B-tile = 64 rows (32 gate + 32 up), BK=64.
__global__ __launch_bounds__(256) void gemm1_mfma(
    const _Float16* __restrict__ xh, const int* __restrict__ qblk,
    const int* __restrict__ qscl, const float* __restrict__ bias,
    const int* __restrict__ cnt, const int* __restrict__ pref,
    const int* __restrict__ meta, const int* __restrict__ tl1,
    _Float16* __restrict__ hbuf) {
    __shared__ int lut[256];
    __shared__ int4 Asb[2][128];        // 16 tok x 8 int4, dbuf (4 KB)
    __shared__ int4 Bsb[2][512];        // 64 rows x 8 int4, dbuf (16 KB)
    __shared__ float exch[4][64][4];    // 4 KB
    int tid = threadIdx.x;
    lut[tid] = fp4h(tid & 15) | (fp4h(tid >> 4) << 16);
    int wave = tid >> 6, lane = tid & 63;
    int bl = lane & 15, kb4 = lane >> 4;
    int rloc = wave * 16 + bl;
    int rs = tid >> 2, kq = tid & 3;    // staging: row, k-quarter
    int tok = tid >> 3, ga = tid & 7;   // A staging (tid<128)
    int nwork = meta[0] << 6;

    for (int w = blockIdx.x; w < nwork; w += gridDim.x) {
        int tile = tl1[w >> 6];
        int fc = w & 63;
        int e = tile >> 8, mt = tile & 255;
        int n = cnt[e];
        int nt = n - mt * 16; if (nt > 16) nt = 16;
        int base = pref[e];
        int t0 = base + mt * 16;
        int f0 = fc * 32;

        long rowg = (long)e * 4096 + ((rs < 32) ? (f0 + rs) : (2048 + f0 + rs - 32));
        const int4* wrow = (const int4*)(qblk + rowg * 512);
        const int* srow = qscl + rowg * 32;
        int tclamp = (tok < nt) ? tok : nt - 1;
        const int4* arow = (const int4*)xh + (long)(t0 + tclamp) * 128;

        // prologue: load + stage kb=0 into buf 0
        int4 q0 = wrow[kq * 2];
        int4 q1 = wrow[kq * 2 + 1];
        int sc = srow[kq >> 1];
        int4 av;
        if (tid < 128) av = arow[ga];
        __syncthreads();
        if (tid < 128) Asb[0][tok * 8 + (ga ^ (tok & 7))] = av;
        {
            int sv = (sc - 112) << 10; sv |= sv << 16;
            int4 o0, o1;
            o0.x = dec2i(lut, q0.x, sv); o0.y = dec2i(lut, q0.y, sv);
            o0.z = dec2i(lut, q0.z, sv); o0.w = dec2i(lut, q0.w, sv);
            o1.x = dec2i(lut, q1.x, sv); o1.y = dec2i(lut, q1.y, sv);
            o1.z = dec2i(lut, q1.z, sv); o1.w = dec2i(lut, q1.w, sv);
            Bsb[0][rs * 8 + ((kq * 2) ^ (rs & 7))] = o0;
            Bsb[0][rs * 8 + ((kq * 2 + 1) ^ (rs & 7))] = o1;
        }
        __syncthreads();

        f32x4 acc = {0.f, 0.f, 0.f, 0.f};
        for (int kb = 0; kb < 16; ++kb) {
            int cur = kb & 1;
            if (kb < 15) {                      // prefetch next step (in flight during MFMA)
                q0 = wrow[(kb + 1) * 8 + kq * 2];
                q1 = wrow[(kb + 1) * 8 + kq * 2 + 1];
                sc = srow[(kb + 1) * 2 + (kq >> 1)];
                if (tid < 128) av = arow[(kb + 1) * 8 + ga];
            }
            #pragma unroll
            for (int ks = 0; ks < 2; ++ks) {
                int g = ks * 4 + kb4;
                XI a, b;
                a.v = Asb[cur][bl * 8 + (g ^ (bl & 7))];
                b.v = Bsb[cur][rloc * 8 + (g ^ (rloc & 7))];
                acc = __builtin_amdgcn_mfma_f32_16x16x32_f16(a.h, b.h, acc, 0, 0, 0);
            }
            if (kb < 15) {                      // write other buffer; one barrier/step
                int nxt = cur ^ 1;
                if (tid < 128) Asb[nxt][tok * 8 + (ga ^ (tok & 7))] = av;
                int sv = (sc - 112) << 10; sv |= sv << 16;
                int4 o0, o1;
                o0.x = dec2i(lut, q0.x, sv); o0.y = dec2i(lut, q0.y, sv);
                o0.z = dec2i(lut, q0.z, sv); o0.w = dec2i(lut, q0.w, sv);
                o1.x = dec2i(lut, q1.x, sv); o1.y = dec2i(lut, q1.y, sv);
                o1.z = dec2i(lut, q1.z, sv); o1.w = dec2i(lut, q1.w, sv);
                Bsb[nxt][rs * 8 + ((kq * 2) ^ (rs & 7))] = o0;
                Bsb[nxt][rs * 8 + ((kq * 2 + 1) ^ (rs & 7))] = o1;
                __syncthreads();
            }
        }
        #pragma unroll
        for (int i = 0; i < 4; ++i) exch[wave][lane][i] = acc[i];
        __syncthreads();
        // epilogue: 16 tok x 32 f
        int fl = tid & 31, wv = fl >> 4, col = fl & 15;
        float bg = bias[(long)e * 4096 + f0 + fl];
        float bu = bias[(long)e * 4096 + 2048 + f0 + fl];
        #pragma unroll
        for (int d = 0; d < 2; ++d) {
            int tk = (tid >> 5) + d * 8;
            int ln = ((tk >> 2) << 4) | col;
            int rg = tk & 3;
            float g = exch[wv][ln][rg] + bg;
            float u = exch[wv + 2][ln][rg] + bu;
            float h = (g / (1.f + expf(-g))) * u;
            if (tk < nt)
                hbuf[(long)(t0 + tk) * FD + f0 + fl] = (_Float16)(h * 0.0625f);  // 2^-4
        }
    }
}

// down GEMM: MFMA, dbuf LDS, pipelined; K split in 2 halves -> y0/y1 (no atomics).
__global__ __launch_bounds__(256) void gemm2_mfma(
    const _Float16* __restrict__ hbuf, const int* __restrict__ qblk,
    const int* __restrict__ qscl, const float* __restrict__ bias,
    const int* __restrict__ cnt, const int* __restrict__ pref,
    const int* __restrict__ meta, const int* __restrict__ tl1,
    float* __restrict__ y0p, float* __restrict__ y1p) {
    __shared__ int lut[256];
    __shared__ int4 Asb[2][128];
    __shared__ int4 Bsb[2][512];
    int tid = threadIdx.x;
    lut[tid] = fp4h(tid & 15) | (fp4h(tid >> 4) << 16);
    int wave = tid >> 6, lane = tid & 63;
    int bl = lane & 15, kb4 = lane >> 4;
    int rloc = wave * 16 + bl;
    int rs = tid >> 2, kq = tid & 3;
    int tok = tid >> 3, ga = tid & 7;
    int nwork = meta[0] << 5;           // 16 h-chunks x 2 k-halves

    for (int w = blockIdx.x; w < nwork; w += gridDim.x) {
        int tile = tl1[w >> 5];
        int sub = w & 31;
        int hc = sub & 15, kh = sub >> 4;
        int e = tile >> 8, mt = tile & 255;
        int n = cnt[e];
        int nt = n - mt * 16; if (nt > 16) nt = 16;
        int base = pref[e];
        int t0 = base + mt * 16;
        int h0 = hc * 64;

        long rowg = (long)e * HD + h0 + rs;
        const int4* wrow = (const int4*)(qblk + rowg * 1024) + (kh * 16) * 8;
        const int* srow = qscl + rowg * 64 + kh * 32;
        int tclamp = (tok < nt) ? tok : nt - 1;
        const int4* arow = (const int4*)hbuf + (long)(t0 + tclamp) * 256 + (kh * 16) * 8;

        int4 q0 = wrow[kq * 2];
        int4 q1 = wrow[kq * 2 + 1];
        int sc = srow[kq >> 1];
        int4 av;
        if (tid < 128) av = arow[ga];
        __syncthreads();
        if (tid < 128) Asb[0][tok * 8 + (ga ^ (tok & 7))] = av;
        {
            int sv = (sc - 112) << 10; sv |= sv << 16;
            int4 o0, o1;
            o0.x = dec2i(lut, q0.x, sv); o0.y = dec2i(lut, q0.y, sv);
            o0.z = dec2i(lut, q0.z, sv); o0.w = dec2i(lut, q0.w, sv);
            o1.x = dec2i(lut, q1.x, sv); o1.y = dec2i(lut, q1.y, sv);
            o1.z = dec2i(lut, q1.z, sv); o1.w = dec2i(lut, q1.w, sv);
            Bsb[0][rs * 8 + ((kq * 2) ^ (rs & 7))] = o0;
            Bsb[0][rs * 8 + ((kq * 2 + 1) ^ (rs & 7))] = o1;
        }
        __syncthreads();

        f32x4 acc = {0.f, 0.f, 0.f, 0.f};
        for (int kb = 0; kb < 16; ++kb) {
            int cur = kb & 1;
            if (kb < 15) {
                q0 = wrow[(kb + 1) * 8 + kq * 2];
                q1 = wrow[(kb + 1) * 8 + kq * 2 + 1];
                sc = srow[(kb + 1) * 2 + (kq >> 1)];
                if (tid < 128) av = arow[(kb + 1) * 8 + ga];
            }
            #pragma unroll
            for (int ks = 0; ks < 2; ++ks) {
                int g = ks * 4 + kb4;
                XI a, b;
                a.v = Asb[cur][bl * 8 + (g ^ (bl & 7))];
                b.v = Bsb[cur][rloc * 8 + (g ^ (rloc & 7))];
                acc = __builtin_amdgcn_mfma_f32_16x16x32_f16(a.h, b.h, acc, 0, 0, 0);
            }
            if (kb < 15) {
                int nxt = cur ^ 1;
                if (tid < 128) Asb[nxt][tok * 8 + (ga ^ (tok & 7))] = av;
                int sv = (sc - 112) << 10; sv |= sv << 16;
                int4 o0, o1;
                o0.x = dec2i(lut, q0.x, sv); o0.y = dec2i(lut, q0.y, sv);
                o0.z = dec2i(lut, q0.z, sv); o0.w = dec2i(lut, q0.w, sv);
                o1.x = dec2i(lut, q1.x, sv); o1.y = dec2i(lut, q1.y, sv);
                o1.z = dec2i(lut, q1.z, sv); o1.w = dec2i(lut, q1.w, sv);
                Bsb[nxt][rs * 8 + ((kq * 2) ^ (rs & 7))] = o0;
                Bsb[nxt][rs * 8 + ((kq * 2 + 1) ^ (rs & 7))] = o1;
                __syncthreads();
            }
        }
        // C: col=lane&15 -> h row; row=(lane>>4)*4+reg -> token
        int hcol = h0 + wave * 16 + bl;
        float bv = (kh == 0) ? bias[(long)e * HD + hcol] : 0.f;
        float* yp = (kh == 0) ? y0p : y1p;
        #pragma unroll
        for (int r = 0; r < 4; ++r) {
            int row = kb4 * 4 + r;
            if (row < nt)
                yp[(long)(t0 + row) * HD + hcol] = acc[r] * 16.f + bv;
        }
        __syncthreads();   // protect LDS before next item's prologue writes
    }
}

__global__ void combine_kernel(const float* __restrict__ y0, const float* __restrict__ y1,
                               const int* __restrict__ slot, const float* __restrict__ topw,
                               float* __restrict__ out) {
    int t = blockIdx.x;
    int i = threadIdx.x;   // 256, float4 each
    int s0 = slot[2 * t], s1 = slot[2 * t + 1];
    float w0 = topw[2 * t], w1 = topw[2 * t + 1];
    float4 a0 = ((const float4*)(y0 + (long)s0 * HD))[i];
    float4 a1 = ((const float4*)(y1 + (long)s0 * HD))[i];
    float4 b0 = ((const float4*)(y0 + (long)s1 * HD))[i];
    float4 b1 = ((const float4*)(y1 + (long)s1 * HD))[i];
    float4 o;
    o.x = w0 * (a0.x + a1.x) + w1 * (b0.x + b1.x);
    o.y = w0 * (a0.y + a1.y) + w1 * (b0.y + b1.y);
    o.z = w0 * (a0.z + a1.z) + w1 * (b0.z + b1.z);
    o.w = w0 * (a0.w + a1.w) + w1 * (b0.w + b1.w);
    ((float4*)(out + (long)t * HD))[i] = o;
}

extern "C" void kernel_launch(void* const* d_in, const int* in_sizes, int n_in,
                              void* d_out, int out_size, void* d_ws, size_t ws_size,
                              hipStream_t stream) {
    const float* x          = (const float*)d_in[0];
    const float* rw         = (const float*)d_in[1];
    const float* bias_gu    = (const float*)d_in[2];
    const float* bias_down  = (const float*)d_in[3];
    const int*   blocks_gu  = (const int*)d_in[4];
    const int*   scales_gu  = (const int*)d_in[5];
    const int*   blocks_down= (const int*)d_in[6];
    const int*   scales_down= (const int*)d_in[7];
    float* out = (float*)d_out;
    int*   wsI = (int*)d_ws;
    float* wsF = (float*)d_ws;
    _Float16* xh   = (_Float16*)(wsI + XH_OFF);
    _Float16* hbuf = (_Float16*)(wsI + HBUF_OFF);
    float*    y0   = wsF + Y0_OFF;
    float*    y1   = wsF + Y1_OFF;

    routing_kernel<<<128, 256, 0, stream>>>(x, rw, wsI + TOPI_OFF, wsF + TOPW_OFF);
    build_kernel<<<1, 256, 0, stream>>>(wsI + TOPI_OFF, wsI + CNT_OFF, wsI + PREF_OFF,
                                        wsI + SLOT_OFF, wsI + INVT_OFF,
                                        wsI + META_OFF, wsI + TL1_OFF);
    gather_kernel<<<256, 256, 0, stream>>>(x, wsI + INVT_OFF, xh);
    gemm1_mfma<<<2048, 256, 0, stream>>>(xh, blocks_gu, scales_gu, bias_gu,
                                         wsI + CNT_OFF, wsI + PREF_OFF,
                                         wsI + META_OFF, wsI + TL1_OFF, hbuf);
    gemm2_mfma<<<1024, 256, 0, stream>>>(hbuf, blocks_down, scales_down, bias_down,
                                         wsI + CNT_OFF, wsI + PREF_OFF,
                                         wsI + META_OFF, wsI + TL1_OFF, y0, y1);
    combine_kernel<<<128, 256, 0, stream>>>(y0, y1, wsI + SLOT_OFF, wsF + TOPW_OFF, out);
}

// Round 16
// 60.740 us; speedup vs baseline: 5.9170x; 1.0022x over previous
//
#include <hip/hip_runtime.h>
#include <hip/hip_fp16.h>
#include <math.h>

#define NE 16
#define HD 1024
#define FD 2048

typedef _Float16 half8 __attribute__((ext_vector_type(8)));
typedef float f32x4 __attribute__((ext_vector_type(4)));

// ws layout (4-byte units) — ws is ~512 MB, plenty.
#define TOPI_OFF 0          // 256 int
#define TOPW_OFF 256        // 256 float
#define CNT_OFF  512        // 16 int
#define PREF_OFF 528        // 16 int
#define SLOT_OFF 544        // 256 int (pair -> slot)
#define INVT_OFF 800        // 256 int (slot -> token)
#define META_OFF 1056       // 1 int: M1
#define TL1_OFF  1060       // 64 int  (e<<8|mt) 16-token tiles
#define HBUF_OFF 4096                   // h  fp16 [256][2048] = 262144 ints
#define Y0_OFF   (HBUF_OFF + 262144)    // y0 f32 [256][1024]
#define Y1_OFF   (Y0_OFF + 262144)      // y1 f32 [256][1024]

union XI { int4 v; half8 h; };

// fp4 e2m1 nibble -> fp16 bits (unscaled)
__device__ __forceinline__ int fp4h(int nib) {
    int c = nib & 7;
    int v;
    if (c == 0) v = 0;
    else if (c == 1) v = 14 << 10;                        // 0.5
    else v = (((c >> 1) + 14) << 10) | ((c & 1) << 9);
    v |= (nib & 8) << 12;
    return v;
}

// LUT byte -> 2 packed fp16 times packed pow2 scale (exact)
__device__ __forceinline__ int dec2i(const int* lut, int byte, int sv) {
    int l = lut[byte & 255];
    __half2 p = *reinterpret_cast<const __half2*>(&l);
    __half2 sc = *reinterpret_cast<const __half2*>(&sv);
    __half2 r = __hmul2(p, sc);
    return *reinterpret_cast<int*>(&r);
}

__global__ void routing_kernel(const float* __restrict__ x, const float* __restrict__ rw,
                               int* __restrict__ top_idx, float* __restrict__ top_w) {
    int t = blockIdx.x;
    int tid = threadIdx.x;          // 256
    int e = tid >> 4, seg = tid & 15;
    const float* xr = x + t * HD + seg * 64;
    const float* wr = rw + e * HD + seg * 64;
    float p = 0.f;
    #pragma unroll 8
    for (int i = 0; i < 64; ++i) p += xr[i] * wr[i];
    __shared__ float part[16][16];
    __shared__ float logit[16];
    part[e][seg] = p;
    __syncthreads();
    if (tid < 16) {
        float s = 0.f;
        #pragma unroll
        for (int i = 0; i < 16; ++i) s += part[tid][i];
        logit[tid] = s;
    }
    __syncthreads();
    if (tid == 0) {
        int i0 = 0; float v0 = logit[0];
        #pragma unroll
        for (int i = 1; i < 16; ++i) { if (logit[i] > v0) { v0 = logit[i]; i0 = i; } }
        int i1 = -1; float v1 = -1e30f;
        #pragma unroll
        for (int i = 0; i < 16; ++i) { if (i != i0 && logit[i] > v1) { v1 = logit[i]; i1 = i; } }
        float w0 = 1.f / (1.f + expf(v1 - v0));
        float w1 = 1.f / (1.f + expf(v0 - v1));
        top_idx[t * 2]     = i0;  top_w[t * 2]     = w0;
        top_idx[t * 2 + 1] = i1;  top_w[t * 2 + 1] = w1;
    }
}

__global__ void build_kernel(const int* __restrict__ top_idx,
                             int* __restrict__ cnt, int* __restrict__ pref,
                             int* __restrict__ slot, int* __restrict__ invtok,
                             int* __restrict__ meta, int* __restrict__ tl1) {
    __shared__ int scnt[16], spref[16], scur[16];
    int tid = threadIdx.x;          // 256
    if (tid < 16) scnt[tid] = 0;
    __syncthreads();
    int e = top_idx[tid];
    atomicAdd(&scnt[e], 1);
    __syncthreads();
    if (tid == 0) {
        int s = 0;
        for (int i = 0; i < 16; ++i) { spref[i] = s; pref[i] = s; cnt[i] = scnt[i]; s += scnt[i]; }
        int m1 = 0;
        for (int i = 0; i < 16; ++i) {
            int ntile1 = (scnt[i] + 15) >> 4;
            for (int m = 0; m < ntile1; ++m) tl1[m1++] = (i << 8) | m;
        }
        meta[0] = m1;
    }
    if (tid < 16) scur[tid] = 0;
    __syncthreads();
    int pos = spref[e] + atomicAdd(&scur[e], 1);
    slot[tid] = pos;
    invtok[pos] = tid >> 1;
}

// gu GEMM + SwiGLU: MFMA, double-buffered LDS, prefetch-pipelined staging.
// A is staged straight from f32 x via invtok (no gather pass): thread (tok=tid>>4,
// jj=tid&15) loads one int4 (4 floats), converts to 4 fp16, writes one int2.
__global__ __launch_bounds__(256) void gemm1_mfma(
    const float* __restrict__ x, const int* __restrict__ invtok,
    const int* __restrict__ qblk, const int* __restrict__ qscl,
    const float* __restrict__ bias,
    const int* __restrict__ cnt, const int* __restrict__ pref,
    const int* __restrict__ meta, const int* __restrict__ tl1,
    _Float16* __restrict__ hbuf) {
    __shared__ int lut[256];
    __shared__ int4 Asb[2][128];        // 16 tok x 8 int4 (fp16), dbuf (4 KB)
    __shared__ int4 Bsb[2][512];        // 64 rows x 8 int4, dbuf (16 KB)
    __shared__ float exch[4][64][4];    // 4 KB
    int tid = threadIdx.x;
    lut[tid] = fp4h(tid & 15) | (fp4h(tid >> 4) << 16);
    int wave = tid >> 6, lane = tid & 63;
    int bl = lane & 15, kb4 = lane >> 4;
    int rloc = wave * 16 + bl;
    int rs = tid >> 2, kq = tid & 3;    // B staging: row, k-quarter
    int tok = tid >> 4, jj = tid & 15;  // A staging: token, f32-int4 index
    int a2idx = (tok * 8 + ((jj >> 1) ^ (tok & 7))) * 2 + (jj & 1);
    int nwork = meta[0] << 6;

    for (int w = blockIdx.x; w < nwork; w += gridDim.x) {
        int tile = tl1[w >> 6];
        int fc = w & 63;
        int e = tile >> 8, mt = tile & 255;
        int n = cnt[e];
        int nt = n - mt * 16; if (nt > 16) nt = 16;
        int base = pref[e];
        int t0 = base + mt * 16;
        int f0 = fc * 32;

        long rowg = (long)e * 4096 + ((rs < 32) ? (f0 + rs) : (2048 + f0 + rs - 32));
        const int4* wrow = (const int4*)(qblk + rowg * 512);
        const int* srow = qscl + rowg * 32;
        int gtok = invtok[t0 + ((tok < nt) ? tok : nt - 1)];
        const int4* arow = (const int4*)x + (long)gtok * 256;   // f32 row = 256 int4

        // prologue: load + stage kb=0 into buf 0
        int4 q0 = wrow[kq * 2];
        int4 q1 = wrow[kq * 2 + 1];
        int sc = srow[kq >> 1];
        int4 av = arow[jj];
        __syncthreads();                 // lut ready
        {
            union { int4 v; float f[4]; } uf; uf.v = av;
            union { _Float16 h[4]; int2 p; } o;
            o.h[0] = (_Float16)uf.f[0]; o.h[1] = (_Float16)uf.f[1];
            o.h[2] = (_Float16)uf.f[2]; o.h[3] = (_Float16)uf.f[3];
            ((int2*)Asb[0])[a2idx] = o.p;
            int sv = (sc - 112) << 10; sv |= sv << 16;
            int4 o0, o1;
            o0.x = dec2i(lut, q0.x, sv); o0.y = dec2i(lut, q0.y, sv);
            o0.z = dec2i(lut, q0.z, sv); o0.w = dec2i(lut, q0.w, sv);
            o1.x = dec2i(lut, q1.x, sv); o1.y = dec2i(lut, q1.y, sv);
            o1.z = dec2i(lut, q1.z, sv); o1.w = dec2i(lut, q1.w, sv);
            Bsb[0][rs * 8 + ((kq * 2) ^ (rs & 7))] = o0;
            Bsb[0][rs * 8 + ((kq * 2 + 1) ^ (rs & 7))] = o1;
        }
        __syncthreads();

        f32x4 acc = {0.f, 0.f, 0.f, 0.f};
        for (int kb = 0; kb < 16; ++kb) {
            int cur = kb & 1;
            if (kb < 15) {                      // prefetch next step
                q0 = wrow[(kb + 1) * 8 + kq * 2];
                q1 = wrow[(kb + 1) * 8 + kq * 2 + 1];
                sc = srow[(kb + 1) * 2 + (kq >> 1)];
                av = arow[(kb + 1) * 16 + jj];
            }
            #pragma unroll
            for (int ks = 0; ks < 2; ++ks) {
                int g = ks * 4 + kb4;
                XI a, b;
                a.v = Asb[cur][bl * 8 + (g ^ (bl & 7))];
                b.v = Bsb[cur][rloc * 8 + (g ^ (rloc & 7))];
                acc = __builtin_amdgcn_mfma_f32_16x16x32_f16(a.h, b.h, acc, 0, 0, 0);
            }
            if (kb < 15) {                      // write other buffer; one barrier/step
                int nxt = cur ^ 1;
                union { int4 v; float f[4]; } uf; uf.v = av;
                union { _Float16 h[4]; int2 p; } o;
                o.h[0] = (_Float16)uf.f[0]; o.h[1] = (_Float16)uf.f[1];
                o.h[2] = (_Float16)uf.f[2]; o.h[3] = (_Float16)uf.f[3];
                ((int2*)Asb[nxt])[a2idx] = o.p;
                int sv = (sc - 112) << 10; sv |= sv << 16;
                int4 o0, o1;
                o0.x = dec2i(lut, q0.x, sv); o0.y = dec2i(lut, q0.y, sv);
                o0.z = dec2i(lut, q0.z, sv); o0.w = dec2i(lut, q0.w, sv);
                o1.x = dec2i(lut, q1.x, sv); o1.y = dec2i(lut, q1.y, sv);
                o1.z = dec2i(lut, q1.z, sv); o1.w = dec2i(lut, q1.w, sv);
                Bsb[nxt][rs * 8 + ((kq * 2) ^ (rs & 7))] = o0;
                Bsb[nxt][rs * 8 + ((kq * 2 + 1) ^ (rs & 7))] = o1;
                __syncthreads();
            }
        }
        #pragma unroll
        for (int i = 0; i < 4; ++i) exch[wave][lane][i] = acc[i];
        __syncthreads();
        // epilogue: 16 tok x 32 f
        int fl = tid & 31, wv = fl >> 4, col = fl & 15;
        float bg = bias[(long)e * 4096 + f0 + fl];
        float bu = bias[(long)e * 4096 + 2048 + f0 + fl];
        #pragma unroll
        for (int d = 0; d < 2; ++d) {
            int tk = (tid >> 5) + d * 8;
            int ln = ((tk >> 2) << 4) | col;
            int rg = tk & 3;
            float g = exch[wv][ln][rg] + bg;
            float u = exch[wv + 2][ln][rg] + bu;
            float h = (g / (1.f + expf(-g))) * u;
            if (tk < nt)
                hbuf[(long)(t0 + tk) * FD + f0 + fl] = (_Float16)(h * 0.0625f);  // 2^-4
        }
        __syncthreads();   // protect LDS before next item's prologue
    }
}

// down GEMM: MFMA, dbuf LDS, pipelined; K split in 2 halves -> y0/y1 (no atomics).
__global__ __launch_bounds__(256) void gemm2_mfma(
    const _Float16* __restrict__ hbuf, const int* __restrict__ qblk,
    const int* __restrict__ qscl, const float* __restrict__ bias,
    const int* __restrict__ cnt, const int* __restrict__ pref,
    const int* __restrict__ meta, const int* __restrict__ tl1,
    float* __restrict__ y0p, float* __restrict__ y1p) {
    __shared__ int lut[256];
    __shared__ int4 Asb[2][128];
    __shared__ int4 Bsb[2][512];
    int tid = threadIdx.x;
    lut[tid] = fp4h(tid & 15) | (fp4h(tid >> 4) << 16);
    int wave = tid >> 6, lane = tid & 63;
    int bl = lane & 15, kb4 = lane >> 4;
    int rloc = wave * 16 + bl;
    int rs = tid >> 2, kq = tid & 3;
    int tok = tid >> 3, ga = tid & 7;
    int nwork = meta[0] << 5;           // 16 h-chunks x 2 k-halves

    for (int w = blockIdx.x; w < nwork; w += gridDim.x) {
        int tile = tl1[w >> 5];
        int sub = w & 31;
        int hc = sub & 15, kh = sub >> 4;
        int e = tile >> 8, mt = tile & 255;
        int n = cnt[e];
        int nt = n - mt * 16; if (nt > 16) nt = 16;
        int base = pref[e];
        int t0 = base + mt * 16;
        int h0 = hc * 64;

        long rowg = (long)e * HD + h0 + rs;
        const int4* wrow = (const int4*)(qblk + rowg * 1024) + (kh * 16) * 8;
        const int* srow = qscl + rowg * 64 + kh * 32;
        int tclamp = (tok < nt) ? tok : nt - 1;
        const int4* arow = (const int4*)hbuf + (long)(t0 + tclamp) * 256 + (kh * 16) * 8;

        int4 q0 = wrow[kq * 2];
        int4 q1 = wrow[kq * 2 + 1];
        int sc = srow[kq >> 1];
        int4 av;
        if (tid < 128) av = arow[ga];
        __syncthreads();
        if (tid < 128) Asb[0][tok * 8 + (ga ^ (tok & 7))] = av;
        {
            int sv = (sc - 112) << 10; sv |= sv << 16;
            int4 o0, o1;
            o0.x = dec2i(lut, q0.x, sv); o0.y = dec2i(lut, q0.y, sv);
            o0.z = dec2i(lut, q0.z, sv); o0.w = dec2i(lut, q0.w, sv);
            o1.x = dec2i(lut, q1.x, sv); o1.y = dec2i(lut, q1.y, sv);
            o1.z = dec2i(lut, q1.z, sv); o1.w = dec2i(lut, q1.w, sv);
            Bsb[0][rs * 8 + ((kq * 2) ^ (rs & 7))] = o0;
            Bsb[0][rs * 8 + ((kq * 2 + 1) ^ (rs & 7))] = o1;
        }
        __syncthreads();

        f32x4 acc = {0.f, 0.f, 0.f, 0.f};
        for (int kb = 0; kb < 16; ++kb) {
            int cur = kb & 1;
            if (kb < 15) {
                q0 = wrow[(kb + 1) * 8 + kq * 2];
                q1 = wrow[(kb + 1) * 8 + kq * 2 + 1];
                sc = srow[(kb + 1) * 2 + (kq >> 1)];
                if (tid < 128) av = arow[(kb + 1) * 8 + ga];
            }
            #pragma unroll
            for (int ks = 0; ks < 2; ++ks) {
                int g = ks * 4 + kb4;
                XI a, b;
                a.v = Asb[cur][bl * 8 + (g ^ (bl & 7))];
                b.v = Bsb[cur][rloc * 8 + (g ^ (rloc & 7))];
                acc = __builtin_amdgcn_mfma_f32_16x16x32_f16(a.h, b.h, acc, 0, 0, 0);
            }
            if (kb < 15) {
                int nxt = cur ^ 1;
                if (tid < 128) Asb[nxt][tok * 8 + (ga ^ (tok & 7))] = av;
                int sv = (sc - 112) << 10; sv |= sv << 16;
                int4 o0, o1;
                o0.x = dec2i(lut, q0.x, sv); o0.y = dec2i(lut, q0.y, sv);
                o0.z = dec2i(lut, q0.z, sv); o0.w = dec2i(lut, q0.w, sv);
                o1.x = dec2i(lut, q1.x, sv); o1.y = dec2i(lut, q1.y, sv);
                o1.z = dec2i(lut, q1.z, sv); o1.w = dec2i(lut, q1.w, sv);
                Bsb[nxt][rs * 8 + ((kq * 2) ^ (rs & 7))] = o0;
                Bsb[nxt][rs * 8 + ((kq * 2 + 1) ^ (rs & 7))] = o1;
                __syncthreads();
            }
        }
        // C: col=lane&15 -> h row; row=(lane>>4)*4+reg -> token
        int hcol = h0 + wave * 16 + bl;
        float bv = (kh == 0) ? bias[(long)e * HD + hcol] : 0.f;
        float* yp = (kh == 0) ? y0p : y1p;
        #pragma unroll
        for (int r = 0; r < 4; ++r) {
            int row = kb4 * 4 + r;
            if (row < nt)
                yp[(long)(t0 + row) * HD + hcol] = acc[r] * 16.f + bv;
        }
        __syncthreads();   // protect LDS before next item's prologue writes
    }
}

__global__ void combine_kernel(const float* __restrict__ y0, const float* __restrict__ y1,
                               const int* __restrict__ slot, const float* __restrict__ topw,
                               float* __restrict__ out) {
    int t = blockIdx.x;
    int i = threadIdx.x;   // 256, float4 each
    int s0 = slot[2 * t], s1 = slot[2 * t + 1];
    float w0 = topw[2 * t], w1 = topw[2 * t + 1];
    float4 a0 = ((const float4*)(y0 + (long)s0 * HD))[i];
    float4 a1 = ((const float4*)(y1 + (long)s0 * HD))[i];
    float4 b0 = ((const float4*)(y0 + (long)s1 * HD))[i];
    float4 b1 = ((const float4*)(y1 + (long)s1 * HD))[i];
    float4 o;
    o.x = w0 * (a0.x + a1.x) + w1 * (b0.x + b1.x);
    o.y = w0 * (a0.y + a1.y) + w1 * (b0.y + b1.y);
    o.z = w0 * (a0.z + a1.z) + w1 * (b0.z + b1.z);
    o.w = w0 * (a0.w + a1.w) + w1 * (b0.w + b1.w);
    ((float4*)(out + (long)t * HD))[i] = o;
}

extern "C" void kernel_launch(void* const* d_in, const int* in_sizes, int n_in,
                              void* d_out, int out_size, void* d_ws, size_t ws_size,
                              hipStream_t stream) {
    const float* x          = (const float*)d_in[0];
    const float* rw         = (const float*)d_in[1];
    const float* bias_gu    = (const float*)d_in[2];
    const float* bias_down  = (const float*)d_in[3];
    const int*   blocks_gu  = (const int*)d_in[4];
    const int*   scales_gu  = (const int*)d_in[5];
    const int*   blocks_down= (const int*)d_in[6];
    const int*   scales_down= (const int*)d_in[7];
    float* out = (float*)d_out;
    int*   wsI = (int*)d_ws;
    float* wsF = (float*)d_ws;
    _Float16* hbuf = (_Float16*)(wsI + HBUF_OFF);
    float*    y0   = wsF + Y0_OFF;
    float*    y1   = wsF + Y1_OFF;

    routing_kernel<<<128, 256, 0, stream>>>(x, rw, wsI + TOPI_OFF, wsF + TOPW_OFF);
    build_kernel<<<1, 256, 0, stream>>>(wsI + TOPI_OFF, wsI + CNT_OFF, wsI + PREF_OFF,
                                        wsI + SLOT_OFF, wsI + INVT_OFF,
                                        wsI + META_OFF, wsI + TL1_OFF);
    gemm1_mfma<<<2048, 256, 0, stream>>>(x, wsI + INVT_OFF, blocks_gu, scales_gu, bias_gu,
                                         wsI + CNT_OFF, wsI + PREF_OFF,
                                         wsI + META_OFF, wsI + TL1_OFF, hbuf);
    gemm2_mfma<<<1024, 256, 0, stream>>>(hbuf, blocks_down, scales_down, bias_down,
                                         wsI + CNT_OFF, wsI + PREF_OFF,
                                         wsI + META_OFF, wsI + TL1_OFF, y0, y1);
    combine_kernel<<<128, 256, 0, stream>>>(y0, y1, wsI + SLOT_OFF, wsF + TOPW_OFF, out);
}